// Round 10
// baseline (302.907 us; speedup 1.0000x reference)
//
#include <hip/hip_runtime.h>
#include <cstdint>
#include <cstddef>

#define IN_F 4096
#define OUT_F 4096
#define NROWS 8192
#define BM 256
#define BN 128
#define BK 32
#define NT (IN_F / BK)   // 128 K-tiles

typedef float f32x4 __attribute__((ext_vector_type(4)));
typedef short s16x8 __attribute__((ext_vector_type(8)));

// round-to-nearest-even fp32 -> bf16
__device__ inline unsigned short f2bf_rne(float f) {
    unsigned int u = __float_as_uint(f);
    u += 0x7FFFu + ((u >> 16) & 1u);
    return (unsigned short)(u >> 16);
}

// Fused: blocks [0, 8192) build W; blocks [8192, 24576) convert x to bf16.
// w[o][t] = 2*norm(o)*sin(pi*(o+1)*(2t+1)/8192); integer-exact reduction mod 16384.
__global__ void prep(const float* __restrict__ x, const float* __restrict__ fc,
                     unsigned short* __restrict__ wb, unsigned short* __restrict__ xb) {
    const int b = blockIdx.x;
    if (b < OUT_F * IN_F / 8 / 256) {
        int gid = b * 256 + threadIdx.x;
        int o = gid >> 9;
        int t0 = (gid & 511) << 3;
        int k = (int)fc[o];
        float amp = 2.0f * rsqrtf(2.0f * (float)IN_F * ((k == 0) ? 2.0f : 1.0f));
        unsigned int op1 = (unsigned int)(k + 1);
        union { s16x8 v; unsigned short s[8]; } p;
#pragma unroll
        for (int j = 0; j < 8; ++j) {
            unsigned int t = (unsigned int)(t0 + j);
            unsigned int r = (op1 * (2u * t + 1u)) & 16383u;
            float ang = (float)r * 3.83495196971410293e-4f;  // pi/8192
            p.s[j] = f2bf_rne(amp * __sinf(ang));
        }
        *reinterpret_cast<s16x8*>(&wb[(size_t)gid * 8]) = p.v;
    } else {
        size_t gid = (size_t)(b - OUT_F * IN_F / 8 / 256) * 256 + threadIdx.x;
        const f32x4* xv = reinterpret_cast<const f32x4*>(x) + gid * 2;
        f32x4 a = xv[0], c = xv[1];
        union { s16x8 v; unsigned short s[8]; } p;
        p.s[0] = f2bf_rne(a[0]); p.s[1] = f2bf_rne(a[1]);
        p.s[2] = f2bf_rne(a[2]); p.s[3] = f2bf_rne(a[3]);
        p.s[4] = f2bf_rne(c[0]); p.s[5] = f2bf_rne(c[1]);
        p.s[6] = f2bf_rne(c[2]); p.s[7] = f2bf_rne(c[3]);
        *reinterpret_cast<s16x8*>(&xb[gid * 8]) = p.v;
    }
}

__device__ inline void wg_barrier() {
    asm volatile("" ::: "memory");
    __builtin_amdgcn_s_barrier();
    asm volatile("" ::: "memory");
}

#define GLD(gsrc, ldst) __builtin_amdgcn_global_load_lds( \
    (const __attribute__((address_space(1))) unsigned int*)(gsrc), \
    (__attribute__((address_space(3))) unsigned int*)(ldst), 16, 0, 0)

// Stage K-tile T into buf[T&1] (A 16KB + B 8KB = 24KB; 6 GLD/thread, 256 thr).
// Proven 0-conflict layout: granule g holds (row=g>>2, kchunk=(g&3)^((g>>3)&3)),
// pre-swizzled global source, linear LDS dest. 64B rows.
#define STAGE(T) do { \
    char* _d = (char*)lds + (((T) & 1) * 24576) + tid * 16; \
    const unsigned short* _sa = gA + (size_t)(T) * BK; \
    const unsigned short* _sb = gB + (size_t)(T) * BK; \
    GLD(_sa,                      _d); \
    GLD(_sa + (size_t)64  * IN_F, _d + 4096); \
    GLD(_sa + (size_t)128 * IN_F, _d + 8192); \
    GLD(_sa + (size_t)192 * IN_F, _d + 12288); \
    GLD(_sb,                      _d + 16384); \
    GLD(_sb + (size_t)64  * IN_F, _d + 20480); \
} while (0)

#define MFMA1(d, a, b) d = __builtin_amdgcn_mfma_f32_16x16x32_bf16(a, b, d, 0, 0, 0)

// Minimal 2-phase tile (guide T3-minimum): STAGE(t+1) -> 12 ds_read(buf t&1)
// -> 32 MFMA (compiler inserts fine-grained lgkmcnt per MFMA) -> vmcnt(0)
// -> barrier. The drain stall is hidden by the CO-RESIDENT second block.
#define TILE(T, DO_STAGE) do { \
    if (DO_STAGE) STAGE((T) + 1); \
    const char* _bb = (const char*)lds + (((T) & 1) * 24576); \
    s16x8 af[8], bf[4]; \
    _Pragma("unroll") \
    for (int m = 0; m < 8; ++m) af[m] = *(const s16x8*)(_bb + aoff + m * 1024); \
    _Pragma("unroll") \
    for (int n = 0; n < 4; ++n) bf[n] = *(const s16x8*)(_bb + boff + n * 1024); \
    __builtin_amdgcn_s_setprio(1); \
    _Pragma("unroll") \
    for (int m = 0; m < 8; ++m) { \
        _Pragma("unroll") \
        for (int n = 0; n < 4; ++n) MFMA1(acc[m][n], af[m], bf[n]); \
    } \
    __builtin_amdgcn_s_setprio(0); \
    asm volatile("s_waitcnt vmcnt(0)" ::: "memory"); \
    wg_barrier(); \
} while (0)

__global__ __launch_bounds__(256, 2) void gemm_dst(
        const unsigned short* __restrict__ xb, const unsigned short* __restrict__ wb,
        const float* __restrict__ bias, float* __restrict__ out) {
    // 2-deep circular buffer: 2 x (A 16KB + B 8KB) = 48 KB -> 2 blocks/CU
    __shared__ unsigned short lds[24576];

    const int tid = threadIdx.x;
    const int lane = tid & 63;
    const int wave = tid >> 6;
    const int wave_m = wave >> 1;   // 0..1 -> 128-row half
    const int wave_n = wave & 1;    // 0..1 -> 64-col half
    const int lr = lane & 15;
    const int kq = lane >> 4;

    const int bid = blockIdx.x;
    // XCD swizzle: 1024 wgs, 128 per XCD; 32 consecutive share the A row-panel
    const int swz = (bid & 7) * 128 + (bid >> 3);
    const int brow = (swz >> 5) * BM;   // 32 row panels
    const int bcol = (swz & 31) * BN;   // 32 col panels

    // ---- stage addressing (R2-proven): granule g = tid + j*256 ->
    // row = g>>2, kchunk = (g&3)^((g>>3)&3) (const across j) ----
    const int srow = tid >> 2;
    const int skq = (tid & 3) ^ ((tid >> 3) & 3);
    const unsigned short* gA = xb + (size_t)(brow + srow) * IN_F + skq * 8;
    const unsigned short* gB = wb + (size_t)(bcol + srow) * IN_F + skq * 8;

    // ---- ds_read addressing (R2-proven 0-conflict): row R, chunk kq ->
    // byte R*64 + ((kq ^ ((R>>1)&3))<<4); R = wave_*128/64 + frag*16 + lr ----
    const int colsw = ((kq ^ ((lr >> 1) & 3)) << 4);
    const int aoff = (wave_m * 128 + lr) * 64 + colsw;            // + m*1024
    const int boff = 16384 + (wave_n * 64 + lr) * 64 + colsw;     // + n*1024

    f32x4 acc[8][4];
#pragma unroll
    for (int m = 0; m < 8; ++m)
#pragma unroll
        for (int n = 0; n < 4; ++n)
            acc[m][n] = (f32x4){0.f, 0.f, 0.f, 0.f};

    // ---- prologue: stage tile 0; drain; barrier ----
    STAGE(0);
    asm volatile("s_waitcnt vmcnt(0)" ::: "memory");
    wg_barrier();

    // ---- main loop: compute buf[t&1], stage t+1 into buf[(t+1)&1] ----
    for (int t = 0; t < 126; t += 2) {
        TILE(t, 1);
        TILE(t + 1, 1);
    }
    TILE(126, 1);
    TILE(127, 0);

    // ---- epilogue: C = acc + bias; 16x16 D layout: col=lane&15, row=(lane>>4)*4+j ----
    const int ccol0 = bcol + wave_n * 64 + lr;
    const int crow0 = brow + wave_m * 128 + kq * 4;
    float bv[4];
#pragma unroll
    for (int n = 0; n < 4; ++n) bv[n] = bias[ccol0 + n * 16];
#pragma unroll
    for (int m = 0; m < 8; ++m) {
#pragma unroll
        for (int j = 0; j < 4; ++j) {
            float* orow = out + (size_t)(crow0 + m * 16 + j) * OUT_F + ccol0;
#pragma unroll
            for (int n = 0; n < 4; ++n)
                orow[n * 16] = acc[m][n][j] + bv[n];
        }
    }
}

// last-resort fallback if workspace is too small (naive on-the-fly DST)
__global__ void fallback_kernel(const float* __restrict__ x, const float* __restrict__ fc,
                                const float* __restrict__ bias, float* __restrict__ out) {
    __shared__ float xrow[IN_F];
    const int o = blockIdx.x * 256 + threadIdx.x;
    const int n = blockIdx.y;
    for (int i = threadIdx.x; i < IN_F; i += 256)
        xrow[i] = x[(size_t)n * IN_F + i];
    __syncthreads();
    const int k = (int)fc[o];
    const float amp = 2.0f * rsqrtf(2.0f * (float)IN_F * ((k == 0) ? 2.0f : 1.0f));
    const unsigned int op1 = (unsigned int)(k + 1);
    float s = 0.f;
    for (int t = 0; t < IN_F; ++t) {
        unsigned int r = (op1 * (2u * (unsigned int)t + 1u)) & 16383u;
        s += xrow[t] * __sinf((float)r * 3.83495196971410293e-4f);
    }
    out[(size_t)n * OUT_F + o] = amp * s + bias[o];
}

extern "C" void kernel_launch(void* const* d_in, const int* in_sizes, int n_in,
                              void* d_out, int out_size, void* d_ws, size_t ws_size,
                              hipStream_t stream) {
    const float* x    = (const float*)d_in[0];
    const float* fc   = (const float*)d_in[1];
    const float* bias = (const float*)d_in[2];
    float* out = (float*)d_out;

    const size_t WBYTES = (size_t)OUT_F * IN_F * 2;   // 32 MB
    const size_t XBYTES = (size_t)NROWS * IN_F * 2;   // 64 MB

    if (ws_size >= WBYTES + XBYTES) {
        unsigned short* wb = (unsigned short*)d_ws;
        unsigned short* xb = (unsigned short*)((char*)d_ws + WBYTES);
        const int wgrid = OUT_F * IN_F / 8 / 256;           // 8192
        const int xgrid = NROWS * IN_F / 8 / 256;           // 16384
        prep<<<wgrid + xgrid, 256, 0, stream>>>(x, fc, wb, xb);
        const int grid = (NROWS / BM) * (OUT_F / BN);       // 1024
        gemm_dst<<<grid, 256, 0, stream>>>(xb, wb, bias, out);
    } else {
        dim3 g(OUT_F / 256, NROWS);
        fallback_kernel<<<g, 256, 0, stream>>>(x, fc, bias, out);
    }
}

// Round 11
// 119.084 us; speedup vs baseline: 2.5436x; 2.5436x over previous
//
#include <hip/hip_runtime.h>
#include <cstdint>
#include <cstddef>

#define IN_F 4096
#define OUT_F 4096
#define NROWS 8192
#define PI_F 3.14159265358979323846f

// y[row] = orthonormal DST-II_4096(x[row]) + bias, computed via:
//   s_n = (-1)^n x_n                                (folded into gather)
//   v = (s_0,s_2,...,s_4094, s_4095,s_4093,...,s_1) (Makhoul reorder, folded)
//   z[m] = v[2m] + i v[2m+1]  (m<2048)              (folded -> direct x gather)
//   Z = CFFT_2048(z)          (Stockham radix-2, verified N=4)
//   V_k = untangle(Z)         (real-FFT recon, verified N1=2)
//   W_k = e^{-i pi k/8192} V_k; C_k = Re W_k; C_{4096-k} = -Im W_k
//   DST[o] = C[4095-o]; y[o] = 2*norm[o]*DST[o] + bias[o]
__global__ __launch_bounds__(256) void dst_row(const float* __restrict__ x,
                                               const float* __restrict__ bias,
                                               float* __restrict__ out) {
    __shared__ float Ar[2048], Ai[2048], Br[2048], Bi[2048];  // 32 KB, SoA
    const int t = threadIdx.x;
    const int row = blockIdx.x;
    const float* xr = x + (size_t)row * IN_F;
    float* yr = out + (size_t)row * OUT_F;

    // ---- gather: z[m] (sign flip for odd source indices already applied) ----
#pragma unroll
    for (int q = 0; q < 8; ++q) {
        const int m = t + q * 256;
        float re, im;
        if (m < 1024) {
            const float4 v = *(const float4*)(xr + 4 * m);      // x[4m..4m+3]
            re = v.x;          // x[4m]    (even -> +)
            im = v.z;          // x[4m+2]  (even -> +)
        } else {
            const float4 v = *(const float4*)(xr + (8188 - 4 * m));
            re = -v.w;         // -x[8191-4m] (odd -> -)
            im = -v.y;         // -x[8189-4m] (odd -> -)
        }
        Ar[m] = re;
        Ai[m] = im;
    }
    __syncthreads();

    // ---- Stockham radix-2 CFFT-2048, 11 stages, ping-pong A<->B ----
    float *sr = Ar, *si = Ai, *dr = Br, *di = Bi;
    for (int s = 0; s < 11; ++s) {
        const int mm = 1024 >> s;          // group size
#pragma unroll
        for (int q = 0; q < 4; ++q) {
            const int b = t + q * 256;     // butterfly id 0..1023
            const int j = b >> (10 - s);   // b / mm
            const int i = b & (mm - 1);    // b % mm
            const int i0 = i + j * 2 * mm;
            const float ar = sr[i0], aim = si[i0];
            const float cr = sr[i0 + mm], ci = si[i0 + mm];
            float sw, cw;
            __sincosf(-PI_F * (float)j / (float)(1 << s), &sw, &cw);
            const float wr = cr * cw - ci * sw;
            const float wi = cr * sw + ci * cw;
            const int o0 = i + j * mm;
            dr[o0] = ar + wr;        di[o0] = aim + wi;
            dr[o0 + 1024] = ar - wr; di[o0 + 1024] = aim - wi;
        }
        __syncthreads();
        float* tp;
        tp = sr; sr = dr; dr = tp;
        tp = si; si = di; di = tp;
    }
    // Z now in (sr, si)

    // ---- untangle + DCT twiddle + DST map + normalize + bias ----
    const float amp1 = 2.0f * rsqrtf(8192.0f);    // o > 0
    const float amp0 = 2.0f * rsqrtf(16384.0f);   // o == 0
#pragma unroll
    for (int q = 0; q < 8; ++q) {
        const int k = t + q * 256;                // 0..2047
        const float zr = sr[k], zi = si[k];
        const int kc = (2048 - k) & 2047;
        const float cr = sr[kc], ci = si[kc];
        // A = (Z_k + conj(Z_kc))/2 ; B = (Z_k - conj(Z_kc))/(2i)
        const float Arr = 0.5f * (zr + cr), Aii = 0.5f * (zi - ci);
        const float Brr = 0.5f * (zi + ci), Bii = 0.5f * (cr - zr);
        // V_k = A + e^{-2 pi i k/4096} * B
        float s2, c2;
        __sincosf(-PI_F * (float)k / 2048.0f, &s2, &c2);
        const float Vr = Arr + Brr * c2 - Bii * s2;
        const float Vi = Aii + Brr * s2 + Bii * c2;
        // W_k = e^{-i pi k/8192} * V_k
        float s3, c3;
        __sincosf(-PI_F * (float)k / 8192.0f, &s3, &c3);
        const float Wr = Vr * c3 - Vi * s3;
        const float Wi = Vr * s3 + Vi * c3;
        // C_k = Wr -> y[4095-k]  (o in 2048..4095, amp1 always)
        const int o1 = 4095 - k;
        yr[o1] = amp1 * Wr + bias[o1];
        if (k > 0) {
            // C_{4096-k} = -Wi -> y[k-1]  (o in 0..2046)
            const int o2 = k - 1;
            const float amp = (o2 == 0) ? amp0 : amp1;
            yr[o2] = amp * (-Wi) + bias[o2];
        } else {
            // Nyquist: V_2048 = ReZ0 - ImZ0; W = e^{-i pi/4} V ->
            // C_2048 = V_2048 * cos(pi/4) -> y[2047]
            const float C2048 = (zr - zi) * 0.70710678118654752f;
            yr[2047] = amp1 * C2048 + bias[2047];
        }
    }
}

extern "C" void kernel_launch(void* const* d_in, const int* in_sizes, int n_in,
                              void* d_out, int out_size, void* d_ws, size_t ws_size,
                              hipStream_t stream) {
    const float* x    = (const float*)d_in[0];
    // d_in[1] (fc) is arange(OUT) by construction; the DST structure assumes it.
    const float* bias = (const float*)d_in[2];
    float* out = (float*)d_out;

    dst_row<<<NROWS, 256, 0, stream>>>(x, bias, out);
}

// Round 12
// 87.606 us; speedup vs baseline: 3.4576x; 1.3593x over previous
//
#include <hip/hip_runtime.h>
#include <cstdint>
#include <cstddef>

#define IN_F 4096
#define OUT_F 4096
#define NROWS 8192
#define PI_F 3.14159265358979323846f

// padded complex index (breaks power-of-2 bank strides; injective)
#define PD(a) ((a) + ((a) >> 4))

__device__ inline float2 cmul(float2 a, float2 b) {
    return make_float2(a.x * b.x - a.y * b.y, a.x * b.y + a.y * b.x);
}

// Precompute twiddle tables into workspace:
//   tw[m]  = e^{-i pi m/1024}, m<1024   (all Stockham stage twiddles)
//   f3[k]  = e^{-i pi k/8192}, k<2048   (final DCT half-shift)
//   f23[k] = e^{-i 5 pi k/8192}        (= e2*e3, folded untangle twiddle)
__global__ void twprep(float2* __restrict__ tw, float2* __restrict__ f3,
                       float2* __restrict__ f23) {
    const int i = blockIdx.x * 256 + threadIdx.x;   // 0..2047
    float s, c;
    if (i < 1024) {
        sincosf(-PI_F * (float)i / 1024.0f, &s, &c);
        tw[i] = make_float2(c, s);
    }
    sincosf(-PI_F * (float)i / 8192.0f, &s, &c);
    f3[i] = make_float2(c, s);
    sincosf(-PI_F * 5.0f * (float)i / 8192.0f, &s, &c);
    f23[i] = make_float2(c, s);
}

// y[row] = orthonormal DST-II_4096(x[row]) + bias  (same math as round 11,
// HW-verified; FFT core now radix-4 Stockham with table twiddles).
__global__ __launch_bounds__(256) void dst_row(const float* __restrict__ x,
                                               const float* __restrict__ bias,
                                               const float2* __restrict__ twg,
                                               const float2* __restrict__ f3,
                                               const float2* __restrict__ f23,
                                               float* __restrict__ out) {
    __shared__ float2 U[2176], V[2176];   // padded 2048-complex ping-pong
    __shared__ float2 TW[1024];
    const int t = threadIdx.x;
    const int row = blockIdx.x;
    const float* xr = x + (size_t)row * IN_F;
    float* yr = out + (size_t)row * OUT_F;

    // ---- twiddle table load + gather (verified mapping, round 11) ----
#pragma unroll
    for (int q = 0; q < 4; ++q) TW[t + q * 256] = twg[t + q * 256];
#pragma unroll
    for (int q = 0; q < 8; ++q) {
        const int m = t + q * 256;
        float re, im;
        if (m < 1024) {
            const float4 v = *(const float4*)(xr + 4 * m);
            re = v.x;  im = v.z;
        } else {
            const float4 v = *(const float4*)(xr + (8188 - 4 * m));
            re = -v.w; im = -v.y;
        }
        U[PD(m)] = make_float2(re, im);
    }
    __syncthreads();

    // ---- 5 radix-4 Stockham stages (composed from verified radix-2 pairs) ----
#pragma unroll
    for (int p = 0; p < 5; ++p) {
        const int s = 2 * p;
        const float2* src = (p & 1) ? V : U;
        float2* dst = (p & 1) ? U : V;
#pragma unroll
        for (int q = 0; q < 2; ++q) {
            const int b = t + q * 256;               // 0..511
            const int j = b >> (9 - s);              // 0..2^s-1
            const int i2 = b & ((1 << (9 - s)) - 1);
            const int base = i2 + (j << (11 - s));
            const float2 x0 = src[PD(base)];
            const float2 x1 = src[PD(base + (1 << (9 - s)))];
            const float2 x2 = src[PD(base + (1 << (10 - s)))];
            const float2 x3 = src[PD(base + (1 << (10 - s)) + (1 << (9 - s)))];
            const float2 u  = TW[j << (9 - s)];
            const float2 u2 = TW[j << (10 - s)];
            const float2 t2 = cmul(u2, x2);
            const float2 t3 = cmul(u2, x3);
            const float2 E = make_float2(x0.x + t2.x, x0.y + t2.y);
            const float2 G = make_float2(x0.x - t2.x, x0.y - t2.y);
            const float2 F = make_float2(x1.x + t3.x, x1.y + t3.y);
            const float2 H = make_float2(x1.x - t3.x, x1.y - t3.y);
            const float2 uF = cmul(u, F);
            const float2 uH = cmul(u, H);
            dst[PD(b)]        = make_float2(E.x + uF.x, E.y + uF.y);
            dst[PD(b + 1024)] = make_float2(E.x - uF.x, E.y - uF.y);
            dst[PD(b + 512)]  = make_float2(G.x + uH.y, G.y - uH.x);  // G - i uH
            dst[PD(b + 1536)] = make_float2(G.x - uH.y, G.y + uH.x);  // G + i uH
        }
        __syncthreads();
    }
    // data now in V (p=4 wrote V)

    // ---- final radix-2 stage (s=10), V -> U ----
#pragma unroll
    for (int q = 0; q < 4; ++q) {
        const int b = t + q * 256;                   // 0..1023
        const float2 a = V[PD(2 * b)];
        const float2 c = V[PD(2 * b + 1)];
        const float2 wc = cmul(TW[b], c);
        U[PD(b)]        = make_float2(a.x + wc.x, a.y + wc.y);
        U[PD(b + 1024)] = make_float2(a.x - wc.x, a.y - wc.y);
    }
    __syncthreads();
    // Z in U

    // ---- untangle + twiddle + DST map (verified round 11; W = A*f3 + B*f23) ----
    const float amp1 = 2.0f * rsqrtf(8192.0f);
    const float amp0 = 2.0f * rsqrtf(16384.0f);
#pragma unroll
    for (int q = 0; q < 8; ++q) {
        const int k = t + q * 256;                   // 0..2047
        const float2 z = U[PD(k)];
        const int kc = (2048 - k) & 2047;
        const float2 zc = U[PD(kc)];
        const float Arr = 0.5f * (z.x + zc.x), Aii = 0.5f * (z.y - zc.y);
        const float Brr = 0.5f * (z.y + zc.y), Bii = 0.5f * (zc.x - z.x);
        const float2 e3 = f3[k];
        const float2 eA = f23[k];
        const float Wr = Arr * e3.x - Aii * e3.y + Brr * eA.x - Bii * eA.y;
        const float Wi = Arr * e3.y + Aii * e3.x + Brr * eA.y + Bii * eA.x;
        const int o1 = 4095 - k;
        yr[o1] = amp1 * Wr + bias[o1];
        if (k > 0) {
            const int o2 = k - 1;
            const float amp = (o2 == 0) ? amp0 : amp1;
            yr[o2] = amp * (-Wi) + bias[o2];
        } else {
            const float C2048 = (z.x - z.y) * 0.70710678118654752f;
            yr[2047] = amp1 * C2048 + bias[2047];
        }
    }
}

// Fallback (round-11 kernel, HW-verified): used only if ws is too small for tables.
__global__ __launch_bounds__(256) void dst_row_fb(const float* __restrict__ x,
                                                  const float* __restrict__ bias,
                                                  float* __restrict__ out) {
    __shared__ float Ar[2048], Ai[2048], Br[2048], Bi[2048];
    const int t = threadIdx.x;
    const int row = blockIdx.x;
    const float* xr = x + (size_t)row * IN_F;
    float* yr = out + (size_t)row * OUT_F;
#pragma unroll
    for (int q = 0; q < 8; ++q) {
        const int m = t + q * 256;
        float re, im;
        if (m < 1024) {
            const float4 v = *(const float4*)(xr + 4 * m);
            re = v.x; im = v.z;
        } else {
            const float4 v = *(const float4*)(xr + (8188 - 4 * m));
            re = -v.w; im = -v.y;
        }
        Ar[m] = re; Ai[m] = im;
    }
    __syncthreads();
    float *sr = Ar, *si = Ai, *dr = Br, *di = Bi;
    for (int s = 0; s < 11; ++s) {
        const int mm = 1024 >> s;
#pragma unroll
        for (int q = 0; q < 4; ++q) {
            const int b = t + q * 256;
            const int j = b >> (10 - s);
            const int i = b & (mm - 1);
            const int i0 = i + j * 2 * mm;
            const float ar = sr[i0], aim = si[i0];
            const float cr = sr[i0 + mm], ci = si[i0 + mm];
            float sw, cw;
            __sincosf(-PI_F * (float)j / (float)(1 << s), &sw, &cw);
            const float wr = cr * cw - ci * sw;
            const float wi = cr * sw + ci * cw;
            const int o0 = i + j * mm;
            dr[o0] = ar + wr;        di[o0] = aim + wi;
            dr[o0 + 1024] = ar - wr; di[o0 + 1024] = aim - wi;
        }
        __syncthreads();
        float* tp;
        tp = sr; sr = dr; dr = tp;
        tp = si; si = di; di = tp;
    }
    const float amp1 = 2.0f * rsqrtf(8192.0f);
    const float amp0 = 2.0f * rsqrtf(16384.0f);
#pragma unroll
    for (int q = 0; q < 8; ++q) {
        const int k = t + q * 256;
        const float zr = sr[k], zi = si[k];
        const int kc = (2048 - k) & 2047;
        const float cr = sr[kc], ci = si[kc];
        const float Arr = 0.5f * (zr + cr), Aii = 0.5f * (zi - ci);
        const float Brr = 0.5f * (zi + ci), Bii = 0.5f * (cr - zr);
        float s2, c2;
        __sincosf(-PI_F * (float)k / 2048.0f, &s2, &c2);
        const float Vr = Arr + Brr * c2 - Bii * s2;
        const float Vi = Aii + Brr * s2 + Bii * c2;
        float s3, c3;
        __sincosf(-PI_F * (float)k / 8192.0f, &s3, &c3);
        const float Wr = Vr * c3 - Vi * s3;
        const float Wi = Vr * s3 + Vi * c3;
        const int o1 = 4095 - k;
        yr[o1] = amp1 * Wr + bias[o1];
        if (k > 0) {
            const int o2 = k - 1;
            const float amp = (o2 == 0) ? amp0 : amp1;
            yr[o2] = amp * (-Wi) + bias[o2];
        } else {
            const float C2048 = (zr - zi) * 0.70710678118654752f;
            yr[2047] = amp1 * C2048 + bias[2047];
        }
    }
}

extern "C" void kernel_launch(void* const* d_in, const int* in_sizes, int n_in,
                              void* d_out, int out_size, void* d_ws, size_t ws_size,
                              hipStream_t stream) {
    const float* x    = (const float*)d_in[0];
    const float* bias = (const float*)d_in[2];
    float* out = (float*)d_out;

    if (ws_size >= 40960) {
        float2* tw  = (float2*)d_ws;                       // 1024 (8 KB)
        float2* f3  = (float2*)((char*)d_ws + 8192);       // 2048 (16 KB)
        float2* f23 = (float2*)((char*)d_ws + 24576);      // 2048 (16 KB)
        twprep<<<8, 256, 0, stream>>>(tw, f3, f23);
        dst_row<<<NROWS, 256, 0, stream>>>(x, bias, tw, f3, f23, out);
    } else {
        dst_row_fb<<<NROWS, 256, 0, stream>>>(x, bias, out);
    }
}

// Round 13
// 79.220 us; speedup vs baseline: 3.8236x; 1.1059x over previous
//
#include <hip/hip_runtime.h>
#include <cstdint>
#include <cstddef>

#define IN_F 4096
#define OUT_F 4096
#define NROWS 8192
#define PI_F 3.14159265358979323846f

// padded complex index (breaks power-of-2 bank strides; injective)
#define PD(a) ((a) + ((a) >> 4))

__device__ inline float2 cmul(float2 a, float2 b) {
    return make_float2(a.x * b.x - a.y * b.y, a.x * b.y + a.y * b.x);
}

// Precompute twiddle tables into workspace:
//   tw[m]  = e^{-i pi m/1024}, m<1024   (all Stockham stage twiddles)
//   f3[k]  = e^{-i pi k/8192}, k<2048   (final DCT half-shift)
//   f23[k] = e^{-i 5 pi k/8192}        (= e2*e3, folded untangle twiddle)
__global__ void twprep(float2* __restrict__ tw, float2* __restrict__ f3,
                       float2* __restrict__ f23) {
    const int i = blockIdx.x * 256 + threadIdx.x;   // 0..2047
    float s, c;
    if (i < 1024) {
        sincosf(-PI_F * (float)i / 1024.0f, &s, &c);
        tw[i] = make_float2(c, s);
    }
    sincosf(-PI_F * (float)i / 8192.0f, &s, &c);
    f3[i] = make_float2(c, s);
    sincosf(-PI_F * 5.0f * (float)i / 8192.0f, &s, &c);
    f23[i] = make_float2(c, s);
}

// y[row] = orthonormal DST-II_4096(x[row]) + bias (round-11-verified math,
// round-12-verified radix-4 table FFT; now 512 threads for 24 waves/CU).
__global__ __launch_bounds__(512) void dst_row(const float* __restrict__ x,
                                               const float* __restrict__ bias,
                                               const float2* __restrict__ twg,
                                               const float2* __restrict__ f3,
                                               const float2* __restrict__ f23,
                                               float* __restrict__ out) {
    __shared__ float2 U[2176], V[2176];   // padded 2048-complex ping-pong
    __shared__ float2 TW[1024];
    const int t = threadIdx.x;
    const int row = blockIdx.x;
    const float* xr = x + (size_t)row * IN_F;
    float* yr = out + (size_t)row * OUT_F;

    // ---- twiddle table load + gather (verified mapping) ----
#pragma unroll
    for (int q = 0; q < 2; ++q) TW[t + q * 512] = twg[t + q * 512];
#pragma unroll
    for (int q = 0; q < 4; ++q) {
        const int m = t + q * 512;
        float re, im;
        if (m < 1024) {
            const float4 v = *(const float4*)(xr + 4 * m);
            re = v.x;  im = v.z;
        } else {
            const float4 v = *(const float4*)(xr + (8188 - 4 * m));
            re = -v.w; im = -v.y;
        }
        U[PD(m)] = make_float2(re, im);
    }
    __syncthreads();

    // ---- 5 radix-4 Stockham stages (verified round 12); 1 butterfly/thread ----
#pragma unroll
    for (int p = 0; p < 5; ++p) {
        const int s = 2 * p;
        const float2* src = (p & 1) ? V : U;
        float2* dst = (p & 1) ? U : V;
        {
            const int b = t;                         // 0..511
            const int j = b >> (9 - s);              // 0..2^s-1
            const int i2 = b & ((1 << (9 - s)) - 1);
            const int base = i2 + (j << (11 - s));
            const float2 x0 = src[PD(base)];
            const float2 x1 = src[PD(base + (1 << (9 - s)))];
            const float2 x2 = src[PD(base + (1 << (10 - s)))];
            const float2 x3 = src[PD(base + (1 << (10 - s)) + (1 << (9 - s)))];
            const float2 u  = TW[j << (9 - s)];
            const float2 u2 = TW[j << (10 - s)];
            const float2 t2 = cmul(u2, x2);
            const float2 t3 = cmul(u2, x3);
            const float2 E = make_float2(x0.x + t2.x, x0.y + t2.y);
            const float2 G = make_float2(x0.x - t2.x, x0.y - t2.y);
            const float2 F = make_float2(x1.x + t3.x, x1.y + t3.y);
            const float2 H = make_float2(x1.x - t3.x, x1.y - t3.y);
            const float2 uF = cmul(u, F);
            const float2 uH = cmul(u, H);
            dst[PD(b)]        = make_float2(E.x + uF.x, E.y + uF.y);
            dst[PD(b + 1024)] = make_float2(E.x - uF.x, E.y - uF.y);
            dst[PD(b + 512)]  = make_float2(G.x + uH.y, G.y - uH.x);  // G - i uH
            dst[PD(b + 1536)] = make_float2(G.x - uH.y, G.y + uH.x);  // G + i uH
        }
        __syncthreads();
    }
    // data now in V (p=4 wrote V)

    // ---- final radix-2 stage (s=10), V -> U ----
#pragma unroll
    for (int q = 0; q < 2; ++q) {
        const int b = t + q * 512;                   // 0..1023
        const float2 a = V[PD(2 * b)];
        const float2 c = V[PD(2 * b + 1)];
        const float2 wc = cmul(TW[b], c);
        U[PD(b)]        = make_float2(a.x + wc.x, a.y + wc.y);
        U[PD(b + 1024)] = make_float2(a.x - wc.x, a.y - wc.y);
    }
    __syncthreads();
    // Z in U

    // ---- untangle + twiddle + DST map (verified; W = A*f3 + B*f23) ----
    const float amp1 = 2.0f * rsqrtf(8192.0f);
    const float amp0 = 2.0f * rsqrtf(16384.0f);
#pragma unroll
    for (int q = 0; q < 4; ++q) {
        const int k = t + q * 512;                   // 0..2047
        const float2 z = U[PD(k)];
        const int kc = (2048 - k) & 2047;
        const float2 zc = U[PD(kc)];
        const float Arr = 0.5f * (z.x + zc.x), Aii = 0.5f * (z.y - zc.y);
        const float Brr = 0.5f * (z.y + zc.y), Bii = 0.5f * (zc.x - z.x);
        const float2 e3 = f3[k];
        const float2 eA = f23[k];
        const float Wr = Arr * e3.x - Aii * e3.y + Brr * eA.x - Bii * eA.y;
        const float Wi = Arr * e3.y + Aii * e3.x + Brr * eA.y + Bii * eA.x;
        const int o1 = 4095 - k;
        yr[o1] = amp1 * Wr + bias[o1];
        if (k > 0) {
            const int o2 = k - 1;
            const float amp = (o2 == 0) ? amp0 : amp1;
            yr[o2] = amp * (-Wi) + bias[o2];
        } else {
            const float C2048 = (z.x - z.y) * 0.70710678118654752f;
            yr[2047] = amp1 * C2048 + bias[2047];
        }
    }
}

// Fallback (round-11 kernel, HW-verified): used only if ws is too small for tables.
__global__ __launch_bounds__(256) void dst_row_fb(const float* __restrict__ x,
                                                  const float* __restrict__ bias,
                                                  float* __restrict__ out) {
    __shared__ float Ar[2048], Ai[2048], Br[2048], Bi[2048];
    const int t = threadIdx.x;
    const int row = blockIdx.x;
    const float* xr = x + (size_t)row * IN_F;
    float* yr = out + (size_t)row * OUT_F;
#pragma unroll
    for (int q = 0; q < 8; ++q) {
        const int m = t + q * 256;
        float re, im;
        if (m < 1024) {
            const float4 v = *(const float4*)(xr + 4 * m);
            re = v.x; im = v.z;
        } else {
            const float4 v = *(const float4*)(xr + (8188 - 4 * m));
            re = -v.w; im = -v.y;
        }
        Ar[m] = re; Ai[m] = im;
    }
    __syncthreads();
    float *sr = Ar, *si = Ai, *dr = Br, *di = Bi;
    for (int s = 0; s < 11; ++s) {
        const int mm = 1024 >> s;
#pragma unroll
        for (int q = 0; q < 4; ++q) {
            const int b = t + q * 256;
            const int j = b >> (10 - s);
            const int i = b & (mm - 1);
            const int i0 = i + j * 2 * mm;
            const float ar = sr[i0], aim = si[i0];
            const float cr = sr[i0 + mm], ci = si[i0 + mm];
            float sw, cw;
            __sincosf(-PI_F * (float)j / (float)(1 << s), &sw, &cw);
            const float wr = cr * cw - ci * sw;
            const float wi = cr * sw + ci * cw;
            const int o0 = i + j * mm;
            dr[o0] = ar + wr;        di[o0] = aim + wi;
            dr[o0 + 1024] = ar - wr; di[o0 + 1024] = aim - wi;
        }
        __syncthreads();
        float* tp;
        tp = sr; sr = dr; dr = tp;
        tp = si; si = di; di = tp;
    }
    const float amp1 = 2.0f * rsqrtf(8192.0f);
    const float amp0 = 2.0f * rsqrtf(16384.0f);
#pragma unroll
    for (int q = 0; q < 8; ++q) {
        const int k = t + q * 256;
        const float zr = sr[k], zi = si[k];
        const int kc = (2048 - k) & 2047;
        const float cr = sr[kc], ci = si[kc];
        const float Arr = 0.5f * (zr + cr), Aii = 0.5f * (zi - ci);
        const float Brr = 0.5f * (zi + ci), Bii = 0.5f * (cr - zr);
        float s2, c2;
        __sincosf(-PI_F * (float)k / 2048.0f, &s2, &c2);
        const float Vr = Arr + Brr * c2 - Bii * s2;
        const float Vi = Aii + Brr * s2 + Bii * c2;
        float s3, c3;
        __sincosf(-PI_F * (float)k / 8192.0f, &s3, &c3);
        const float Wr = Vr * c3 - Vi * s3;
        const float Wi = Vr * s3 + Vi * c3;
        const int o1 = 4095 - k;
        yr[o1] = amp1 * Wr + bias[o1];
        if (k > 0) {
            const int o2 = k - 1;
            const float amp = (o2 == 0) ? amp0 : amp1;
            yr[o2] = amp * (-Wi) + bias[o2];
        } else {
            const float C2048 = (zr - zi) * 0.70710678118654752f;
            yr[2047] = amp1 * C2048 + bias[2047];
        }
    }
}

extern "C" void kernel_launch(void* const* d_in, const int* in_sizes, int n_in,
                              void* d_out, int out_size, void* d_ws, size_t ws_size,
                              hipStream_t stream) {
    const float* x    = (const float*)d_in[0];
    const float* bias = (const float*)d_in[2];
    float* out = (float*)d_out;

    if (ws_size >= 40960) {
        float2* tw  = (float2*)d_ws;                       // 1024 (8 KB)
        float2* f3  = (float2*)((char*)d_ws + 8192);       // 2048 (16 KB)
        float2* f23 = (float2*)((char*)d_ws + 24576);      // 2048 (16 KB)
        twprep<<<8, 256, 0, stream>>>(tw, f3, f23);
        dst_row<<<NROWS, 512, 0, stream>>>(x, bias, tw, f3, f23, out);
    } else {
        dst_row_fb<<<NROWS, 256, 0, stream>>>(x, bias, out);
    }
}